// Round 1
// baseline (324.783 us; speedup 1.0000x reference)
//
#include <hip/hip_runtime.h>
#include <hip/hip_bf16.h>
#include <stdint.h>

#define BB   16
#define JJ   256
#define KK   384
#define NROW (BB * JJ)          // 4096
#define NPOS ((size_t)BB * JJ * KK) // 1572864

// ws layout (bytes)
#define WS_FLAG  0                         // int[1] : 1 => mask is byte-per-element
#define WS_VALID 64                        // int[4096]
#define WS_SEL   (WS_VALID + NROW * 4)     // int[16*32]
#define WS_PART  (WS_SEL + 512 * 4)        // float[512][33]
#define WS_REPB  (WS_PART + 512 * 33 * 4)  // float[16][32]

__device__ __forceinline__ uint32_t rotl32(uint32_t x, int r) {
  return (x << r) | (x >> (32 - r));
}

// threefry2x32 with key (0, 42)  == jax.random.key(42)
__device__ __forceinline__ void threefry2x32_k42(uint32_t c0, uint32_t c1,
                                                 uint32_t& o0, uint32_t& o1) {
  const uint32_t ks0 = 0u, ks1 = 42u, ks2 = 0x1BD11BDAu ^ 0u ^ 42u;
  uint32_t x0 = c0 + ks0, x1 = c1 + ks1;
#define TFR(r) { x0 += x1; x1 = rotl32(x1, r); x1 ^= x0; }
  TFR(13) TFR(15) TFR(26) TFR(6)   x0 += ks1; x1 += ks2 + 1u;
  TFR(17) TFR(29) TFR(16) TFR(24)  x0 += ks2; x1 += ks0 + 2u;
  TFR(13) TFR(15) TFR(26) TFR(6)   x0 += ks0; x1 += ks1 + 3u;
  TFR(17) TFR(29) TFR(16) TFR(24)  x0 += ks1; x1 += ks2 + 4u;
  TFR(13) TFR(15) TFR(26) TFR(6)   x0 += ks2; x1 += ks0 + 5u;
#undef TFR
  o0 = x0; o1 = x1;
}

// jax_threefry_partitionable=True (default since jax 0.4.30):
// bits[t] = o0 ^ o1 of threefry(key, (hi32(t)=0, lo32(t)=t))
__device__ __forceinline__ uint32_t jax_bits(uint32_t t) {
  uint32_t o0, o1;
  threefry2x32_k42(0u, t, o0, o1);
  return o0 ^ o1;
}

// --- 1. detect mask element width: any 32-bit word > 1 => byte mask ---
__global__ void k_detect(const uint32_t* __restrict__ mw, int* __restrict__ flag) {
  __shared__ int any_big;
  if (threadIdx.x == 0) any_big = 0;
  __syncthreads();
  int local = 0;
  for (int i = threadIdx.x; i < 1024; i += 256)
    if (mw[i] > 1u) local = 1;
  if (local) atomicOr(&any_big, 1);
  __syncthreads();
  if (threadIdx.x == 0) flag[0] = any_big;
}

// --- 2. valid[b*256+j] = any(mask[b,j,:,:]) ; one wave per row ---
__global__ __launch_bounds__(256) void k_valid(const void* __restrict__ maskp,
                                               const int* __restrict__ flag,
                                               int* __restrict__ valid) {
  const int row = blockIdx.x * 4 + (threadIdx.x >> 6);
  const int lane = threadIdx.x & 63;
  const size_t base = (size_t)row * KK;
  int v = 0;
  if (flag[0]) {
    const uint8_t* m = (const uint8_t*)maskp;
    for (int k = lane; k < KK; k += 64) v |= (m[base + k] != 0);
  } else {
    const int* m = (const int*)maskp;
    for (int k = lane; k < KK; k += 64) v |= (m[base + k] != 0);
  }
  const unsigned long long bal = __ballot(v);
  if (lane == 0) valid[row] = (bal != 0ull) ? 1 : 0;
}

// --- 3. per-batch top-S gumbel selection among valid rows ---
// order(gumbel) == order(bits >> 9); ties -> smaller j (lax.top_k stability).
__global__ void k_select(const int* __restrict__ valid,
                         const int* __restrict__ sample_size,
                         int* __restrict__ sel) {
  const int b = blockIdx.x;      // 16 blocks
  const int lane = threadIdx.x;  // 64 threads
  uint32_t comp[4];
#pragma unroll
  for (int q = 0; q < 4; ++q) {
    const int j = lane * 4 + q;                 // covers 0..255
    const uint32_t t = (uint32_t)(b * 256 + j);
    const uint32_t ub = jax_bits(t) >> 9;       // 23-bit uniform mantissa key
    const uint32_t key = valid[b * 256 + j] ? (ub + 1u) : 0u; // 0 = invalid
    comp[q] = (key << 8) | (uint32_t)(255 - j); // unique, tie->smaller j wins
  }
  int S = sample_size[0];
  if (S > 32) S = 32;
  for (int s = 0; s < S; ++s) {
    uint32_t wm = comp[0];
    wm = comp[1] > wm ? comp[1] : wm;
    wm = comp[2] > wm ? comp[2] : wm;
    wm = comp[3] > wm ? comp[3] : wm;
#pragma unroll
    for (int off = 32; off; off >>= 1) {
      const uint32_t o = __shfl_xor(wm, off);
      wm = o > wm ? o : wm;
    }
    if (wm == 0u) {
      if (lane == 0) sel[b * 32 + s] = 0;  // degenerate (never in practice)
    } else {
#pragma unroll
      for (int q = 0; q < 4; ++q) {
        if (comp[q] == wm) {               // exactly one lane/slot matches
          sel[b * 32 + s] = 255 - (int)(comp[q] & 0xFFu);
          comp[q] = 0u;
        }
      }
    }
  }
}

// --- 4. image branch: h through 4 layers, masked partial sums per (b,s) ---
__global__ __launch_bounds__(384) void k_image(
    const float* __restrict__ Imodel, const float* __restrict__ Iobs,
    const float* __restrict__ md, const void* __restrict__ maskp,
    const int* __restrict__ flag, const int* __restrict__ sel,
    const int* __restrict__ sample_size,
    const float* __restrict__ W_in, const float* __restrict__ b_in,
    const float* __restrict__ Wd, const float* __restrict__ bd,
    float* __restrict__ partial) {
  const int blk = blockIdx.x;        // 512 = 16 b * 32 s
  const int b = blk >> 5, s = blk & 31;
  const bool active = (s < sample_size[0]);
  const int j = sel[b * 32 + s] & 255;
  const int k = threadIdx.x;         // 0..383
  const size_t p = ((size_t)(b * JJ + j)) * KK + k;

  float in[8];
  in[0] = Imodel[p];
  in[1] = Iobs[p];
  const float* mp = md + p * 6;
#pragma unroll
  for (int c = 0; c < 6; ++c) in[2 + c] = mp[c];

  float m;
  if (flag[0]) m = (((const uint8_t*)maskp)[p] != 0) ? 1.f : 0.f;
  else         m = (((const int*)maskp)[p] != 0) ? 1.f : 0.f;
  if (!active) m = 0.f;

  float h[32];
#pragma unroll
  for (int n = 0; n < 32; ++n) {
    float acc = b_in[n];
#pragma unroll
    for (int c = 0; c < 8; ++c) acc = fmaf(in[c], W_in[c * 32 + n], acc);
    h[n] = acc;   // NOTE: no relu on input layer (matches reference)
  }
#pragma unroll
  for (int d = 0; d < 3; ++d) {
    const float* Wl = Wd + d * 1024;
    const float* bl = bd + d * 32;
    float a[32];
#pragma unroll
    for (int n = 0; n < 32; ++n) a[n] = bl[n];
#pragma unroll
    for (int mm = 0; mm < 32; ++mm) {
      const float hm = h[mm];
#pragma unroll
      for (int n = 0; n < 32; ++n) a[n] = fmaf(hm, Wl[mm * 32 + n], a[n]);
    }
#pragma unroll
    for (int n = 0; n < 32; ++n) h[n] = fmaxf(a[n], 0.f);
  }

  // deterministic block reduction: wave shuffles then cross-wave via LDS
  __shared__ float red[6 * 33];
  const int wave = threadIdx.x >> 6, lane = threadIdx.x & 63;
#pragma unroll
  for (int n = 0; n < 32; ++n) {
    float v = h[n] * m;
#pragma unroll
    for (int off = 32; off; off >>= 1) v += __shfl_xor(v, off);
    if (lane == 0) red[wave * 33 + n] = v;
  }
  {
    float v = m;
#pragma unroll
    for (int off = 32; off; off >>= 1) v += __shfl_xor(v, off);
    if (lane == 0) red[wave * 33 + 32] = v;
  }
  __syncthreads();
  if (threadIdx.x < 33) {
    float t = 0.f;
#pragma unroll
    for (int w = 0; w < 6; ++w) t += red[w * 33 + threadIdx.x];
    partial[blk * 33 + threadIdx.x] = t;
  }
}

// --- 5. reduce partials -> rep_bias[b][n] = b_lin[n] + sum/cnt ---
__global__ void k_rep(const float* __restrict__ partial,
                      const float* __restrict__ b_lin,
                      float* __restrict__ rep_bias) {
  const int b = blockIdx.x, n = threadIdx.x;  // 16 x 32
  float sum = 0.f, cnt = 0.f;
  for (int s = 0; s < 32; ++s) {
    sum += partial[(b * 32 + s) * 33 + n];
    cnt += partial[(b * 32 + s) * 33 + 32];
  }
  rep_bias[b * 32 + n] = b_lin[n] + sum / cnt;
}

// --- 6. main pass over all B*J*K positions ---
__global__ __launch_bounds__(256) void k_scale(
    const float* __restrict__ md, const void* __restrict__ maskp,
    const int* __restrict__ flag,
    const float* __restrict__ W_lin, const float* __restrict__ rep_bias,
    const float* __restrict__ Wd, const float* __restrict__ bd,
    const float* __restrict__ W_out, const float* __restrict__ b_out,
    float* __restrict__ out) {
  const int blk = blockIdx.x;
  const int bq = blk / 384;  // J*K/256 = 384 blocks per batch -> uniform
  const size_t idx = (size_t)blk * 256 + threadIdx.x;

  float mv[6];
  const float* mp = md + idx * 6;
#pragma unroll
  for (int c = 0; c < 6; ++c) mv[c] = mp[c];

  bool mk;
  if (flag[0]) mk = (((const uint8_t*)maskp)[idx] != 0);
  else         mk = (((const int*)maskp)[idx] != 0);

  const float* rb = rep_bias + bq * 32;
  float h[32];
#pragma unroll
  for (int n = 0; n < 32; ++n) {
    float acc = rb[n];  // b_lin_in + image_rep folded
#pragma unroll
    for (int c = 0; c < 6; ++c) acc = fmaf(mv[c], W_lin[c * 32 + n], acc);
    h[n] = acc;  // no relu on input layer
  }
#pragma unroll
  for (int d = 0; d < 3; ++d) {
    const float* Wl = Wd + d * 1024;
    const float* bl = bd + d * 32;
    float a[32];
#pragma unroll
    for (int n = 0; n < 32; ++n) a[n] = bl[n];
#pragma unroll
    for (int m = 0; m < 32; ++m) {
      const float hm = h[m];
#pragma unroll
      for (int n = 0; n < 32; ++n) a[n] = fmaf(hm, Wl[m * 32 + n], a[n]);
    }
#pragma unroll
    for (int n = 0; n < 32; ++n) h[n] = fmaxf(a[n], 0.f);
  }
  float o = b_out[0];
#pragma unroll
  for (int n = 0; n < 32; ++n) o = fmaf(h[n], W_out[n], o);
  out[idx] = mk ? o : 0.0f;
}

extern "C" void kernel_launch(void* const* d_in, const int* in_sizes, int n_in,
                              void* d_out, int out_size, void* d_ws, size_t ws_size,
                              hipStream_t stream) {
  const float* Imodel   = (const float*)d_in[0];
  const float* Iobs     = (const float*)d_in[1];
  const float* metadata = (const float*)d_in[2];
  const void*  mask     = d_in[3];
  const int*   sample_size = (const int*)d_in[4];
  const float* W_img_in = (const float*)d_in[5];
  const float* b_img_in = (const float*)d_in[6];
  const float* W_img    = (const float*)d_in[7];
  const float* b_img    = (const float*)d_in[8];
  const float* W_lin_in = (const float*)d_in[9];
  const float* b_lin_in = (const float*)d_in[10];
  const float* W_mlp    = (const float*)d_in[11];
  const float* b_mlp    = (const float*)d_in[12];
  const float* W_out    = (const float*)d_in[13];
  const float* b_out    = (const float*)d_in[14];
  float* out = (float*)d_out;

  char* ws = (char*)d_ws;
  int*   flag     = (int*)(ws + WS_FLAG);
  int*   valid    = (int*)(ws + WS_VALID);
  int*   sel      = (int*)(ws + WS_SEL);
  float* partial  = (float*)(ws + WS_PART);
  float* rep_bias = (float*)(ws + WS_REPB);

  k_detect<<<1, 256, 0, stream>>>((const uint32_t*)mask, flag);
  k_valid<<<NROW / 4, 256, 0, stream>>>(mask, flag, valid);
  k_select<<<BB, 64, 0, stream>>>(valid, sample_size, sel);
  k_image<<<BB * 32, 384, 0, stream>>>(Imodel, Iobs, metadata, mask, flag, sel,
                                       sample_size, W_img_in, b_img_in, W_img,
                                       b_img, partial);
  k_rep<<<BB, 32, 0, stream>>>(partial, b_lin_in, rep_bias);
  k_scale<<<(int)(NPOS / 256), 256, 0, stream>>>(metadata, mask, flag, W_lin_in,
                                                 rep_bias, W_mlp, b_mlp, W_out,
                                                 b_out, out);
}

// Round 2
// 284.397 us; speedup vs baseline: 1.1420x; 1.1420x over previous
//
#include <hip/hip_runtime.h>
#include <hip/hip_bf16.h>
#include <stdint.h>

#define BB   16
#define JJ   256
#define KK   384
#define NROW (BB * JJ)               // 4096
#define NPOS ((size_t)BB * JJ * KK)  // 1572864

// ws layout (bytes)
#define WS_FLAG  0                         // int[1] : 1 => mask is byte-per-element
#define WS_SEL   64                        // int[16*32]
#define WS_PART  (WS_SEL + 512 * 4)        // float[512][33]
#define WS_REPB  (WS_PART + 512 * 33 * 4)  // float[16][32]

__device__ __forceinline__ uint32_t rotl32(uint32_t x, int r) {
  return (x << r) | (x >> (32 - r));
}

// threefry2x32 with key (0, 42)  == jax.random.key(42)
__device__ __forceinline__ void threefry2x32_k42(uint32_t c0, uint32_t c1,
                                                 uint32_t& o0, uint32_t& o1) {
  const uint32_t ks0 = 0u, ks1 = 42u, ks2 = 0x1BD11BDAu ^ 0u ^ 42u;
  uint32_t x0 = c0 + ks0, x1 = c1 + ks1;
#define TFR(r) { x0 += x1; x1 = rotl32(x1, r); x1 ^= x0; }
  TFR(13) TFR(15) TFR(26) TFR(6)   x0 += ks1; x1 += ks2 + 1u;
  TFR(17) TFR(29) TFR(16) TFR(24)  x0 += ks2; x1 += ks0 + 2u;
  TFR(13) TFR(15) TFR(26) TFR(6)   x0 += ks0; x1 += ks1 + 3u;
  TFR(17) TFR(29) TFR(16) TFR(24)  x0 += ks1; x1 += ks2 + 4u;
  TFR(13) TFR(15) TFR(26) TFR(6)   x0 += ks2; x1 += ks0 + 5u;
#undef TFR
  o0 = x0; o1 = x1;
}

// jax_threefry_partitionable=True (default since jax 0.4.30):
// bits[t] = o0 ^ o1 of threefry(key, (hi32(t)=0, lo32(t)=t))
__device__ __forceinline__ uint32_t jax_bits(uint32_t t) {
  uint32_t o0, o1;
  threefry2x32_k42(0u, t, o0, o1);
  return o0 ^ o1;
}

// --- 1. fused: mask-width detect + row-validity + per-batch top-S selection ---
// one block per batch; 256 threads (4 waves)
__global__ __launch_bounds__(256) void k_prep(const void* __restrict__ maskp,
                                              const int* __restrict__ sample_size,
                                              int* __restrict__ flag_out,
                                              int* __restrict__ sel) {
  __shared__ int s_flag;
  __shared__ int s_valid[256];
  const int b = blockIdx.x, t = threadIdx.x;

  // detect: any 32-bit word in the first 4KB > 1 => byte-per-element mask
  if (t == 0) s_flag = 0;
  __syncthreads();
  {
    const uint32_t* mw = (const uint32_t*)maskp;
    int big = 0;
    for (int i = t; i < 1024; i += 256)
      if (mw[i] > 1u) big = 1;
    if (big) atomicOr(&s_flag, 1);
  }
  __syncthreads();
  const int flag = s_flag;
  if (b == 0 && t == 0) flag_out[0] = flag;

  // validity of row j = t of this batch
  {
    const size_t base = ((size_t)(b * JJ + t)) * KK;
    int v = 0;
    if (flag) {
      const uint32_t* r = (const uint32_t*)((const uint8_t*)maskp + base);
      for (int i = 0; i < KK / 4; ++i) v |= (r[i] != 0u);
    } else {
      const int* r = (const int*)maskp + base;
      for (int i = 0; i < KK; ++i) v |= (r[i] != 0);
    }
    s_valid[t] = v;
  }
  __syncthreads();

  // top-S gumbel selection on wave 0.
  // order(gumbel) == order(bits >> 9); ties -> smaller j (lax.top_k stability).
  if (t < 64) {
    uint32_t comp[4];
#pragma unroll
    for (int q = 0; q < 4; ++q) {
      const int j = t * 4 + q;
      const uint32_t tt = (uint32_t)(b * 256 + j);
      const uint32_t ub = jax_bits(tt) >> 9;
      const uint32_t key = s_valid[j] ? (ub + 1u) : 0u;
      comp[q] = (key << 8) | (uint32_t)(255 - j);
    }
    int S = sample_size[0];
    if (S > 32) S = 32;
    for (int s = 0; s < S; ++s) {
      uint32_t wm = comp[0];
      wm = comp[1] > wm ? comp[1] : wm;
      wm = comp[2] > wm ? comp[2] : wm;
      wm = comp[3] > wm ? comp[3] : wm;
#pragma unroll
      for (int off = 32; off; off >>= 1) {
        const uint32_t o = __shfl_xor(wm, off);
        wm = o > wm ? o : wm;
      }
      if (wm == 0u) {
        if (t == 0) sel[b * 32 + s] = 0;
      } else {
#pragma unroll
        for (int q = 0; q < 4; ++q) {
          if (comp[q] == wm) {
            sel[b * 32 + s] = 255 - (int)(comp[q] & 0xFFu);
            comp[q] = 0u;
          }
        }
      }
    }
  }
}

// --- 2. image branch: one block per (b,s); 192 threads x 2 positions ---
__global__ __launch_bounds__(192, 1) void k_image(
    const float* __restrict__ Imodel, const float* __restrict__ Iobs,
    const float* __restrict__ md, const void* __restrict__ maskp,
    const int* __restrict__ flag, const int* __restrict__ sel,
    const int* __restrict__ sample_size,
    const float* __restrict__ W_in, const float* __restrict__ b_in,
    const float* __restrict__ Wd, const float* __restrict__ bd,
    float* __restrict__ partial) {
  const int blk = blockIdx.x;        // 512 = 16 b * 32 s
  const int b = blk >> 5, s = blk & 31;
  const bool active = (s < sample_size[0]);
  const int j = sel[b * 32 + s] & 255;
  const size_t base = ((size_t)(b * JJ + j)) * KK + threadIdx.x * 2;

  // inputs for two consecutive k positions
  float2 im = *(const float2*)(Imodel + base);
  float2 io = *(const float2*)(Iobs + base);
  const float4* mp4 = (const float4*)(md + base * 6);
  const float4 v0 = mp4[0], v1 = mp4[1], v2 = mp4[2];
  float in0[8] = {im.x, io.x, v0.x, v0.y, v0.z, v0.w, v1.x, v1.y};
  float in1[8] = {im.y, io.y, v1.z, v1.w, v2.x, v2.y, v2.z, v2.w};

  float m0, m1;
  if (flag[0]) {
    const uint8_t* m8 = (const uint8_t*)maskp + base;
    m0 = m8[0] ? 1.f : 0.f;
    m1 = m8[1] ? 1.f : 0.f;
  } else {
    const int* mi = (const int*)maskp + base;
    m0 = mi[0] ? 1.f : 0.f;
    m1 = mi[1] ? 1.f : 0.f;
  }
  if (!active) { m0 = 0.f; m1 = 0.f; }

  float h0[32], h1[32];
#pragma unroll
  for (int n = 0; n < 32; ++n) {
    float a0 = b_in[n], a1 = b_in[n];
#pragma unroll
    for (int c = 0; c < 8; ++c) {
      const float w = W_in[c * 32 + n];
      a0 = fmaf(in0[c], w, a0);
      a1 = fmaf(in1[c], w, a1);
    }
    h0[n] = a0; h1[n] = a1;   // no relu on input layer (matches reference)
  }
#pragma unroll
  for (int d = 0; d < 3; ++d) {
    const float* Wl = Wd + d * 1024;
    const float* bl = bd + d * 32;
    float a0[32], a1[32];
#pragma unroll
    for (int n = 0; n < 32; ++n) { a0[n] = bl[n]; a1[n] = bl[n]; }
#pragma unroll
    for (int m = 0; m < 32; ++m) {
      const float hm0 = h0[m], hm1 = h1[m];
#pragma unroll
      for (int n = 0; n < 32; ++n) {
        const float w = Wl[m * 32 + n];
        a0[n] = fmaf(hm0, w, a0[n]);
        a1[n] = fmaf(hm1, w, a1[n]);
      }
    }
#pragma unroll
    for (int n = 0; n < 32; ++n) {
      h0[n] = fmaxf(a0[n], 0.f);
      h1[n] = fmaxf(a1[n], 0.f);
    }
  }

  // masked partial sums over the block (3 waves): 32 h-sums + count
  __shared__ float red[3 * 33];
  const int wave = threadIdx.x >> 6, lane = threadIdx.x & 63;
#pragma unroll
  for (int n = 0; n < 32; ++n) {
    float v = h0[n] * m0 + h1[n] * m1;
#pragma unroll
    for (int off = 32; off; off >>= 1) v += __shfl_xor(v, off);
    if (lane == 0) red[wave * 33 + n] = v;
  }
  {
    float v = m0 + m1;
#pragma unroll
    for (int off = 32; off; off >>= 1) v += __shfl_xor(v, off);
    if (lane == 0) red[wave * 33 + 32] = v;
  }
  __syncthreads();
  if (threadIdx.x < 33) {
    partial[blk * 33 + threadIdx.x] =
        red[threadIdx.x] + red[33 + threadIdx.x] + red[66 + threadIdx.x];
  }
}

// --- 3. reduce partials -> rep_bias[b][n] = b_lin[n] + sum/cnt ---
__global__ void k_rep(const float* __restrict__ partial,
                      const float* __restrict__ b_lin,
                      float* __restrict__ rep_bias) {
  const int b = blockIdx.x, n = threadIdx.x;  // 16 x 32
  float sum = 0.f, cnt = 0.f;
  for (int s = 0; s < 32; ++s) {
    sum += partial[(b * 32 + s) * 33 + n];
    cnt += partial[(b * 32 + s) * 33 + 32];
  }
  rep_bias[b * 32 + n] = b_lin[n] + sum / cnt;
}

// --- 4. main pass: 2 positions per thread, weights via uniform s_loads ---
__global__ __launch_bounds__(256, 1) void k_scale(
    const float* __restrict__ md, const void* __restrict__ maskp,
    const int* __restrict__ flag,
    const float* __restrict__ W_lin, const float* __restrict__ rep_bias,
    const float* __restrict__ Wd, const float* __restrict__ bd,
    const float* __restrict__ W_out, const float* __restrict__ b_out,
    float* __restrict__ out) {
  const int blk = blockIdx.x;          // 3072 blocks
  const int bq = blk / 192;            // 192 blocks per batch (512 pos each)
  const size_t base = (size_t)blk * 512 + (size_t)threadIdx.x * 2;

  const float4* mp4 = (const float4*)(md + base * 6);
  const float4 v0 = mp4[0], v1 = mp4[1], v2 = mp4[2];
  float in0[6] = {v0.x, v0.y, v0.z, v0.w, v1.x, v1.y};
  float in1[6] = {v1.z, v1.w, v2.x, v2.y, v2.z, v2.w};

  bool mk0, mk1;
  if (flag[0]) {
    const uint8_t* m8 = (const uint8_t*)maskp + base;
    mk0 = (m8[0] != 0); mk1 = (m8[1] != 0);
  } else {
    const int* mi = (const int*)maskp + base;
    mk0 = (mi[0] != 0); mk1 = (mi[1] != 0);
  }

  const float* rb = rep_bias + bq * 32;   // uniform -> s_load
  float h0[32], h1[32];
#pragma unroll
  for (int n = 0; n < 32; ++n) {
    const float bias = rb[n];             // b_lin_in + image_rep folded
    float a0 = bias, a1 = bias;
#pragma unroll
    for (int c = 0; c < 6; ++c) {
      const float w = W_lin[c * 32 + n];
      a0 = fmaf(in0[c], w, a0);
      a1 = fmaf(in1[c], w, a1);
    }
    h0[n] = a0; h1[n] = a1;               // no relu on input layer
  }
#pragma unroll
  for (int d = 0; d < 3; ++d) {
    const float* Wl = Wd + d * 1024;
    const float* bl = bd + d * 32;
    float a0[32], a1[32];
#pragma unroll
    for (int n = 0; n < 32; ++n) { a0[n] = bl[n]; a1[n] = bl[n]; }
#pragma unroll
    for (int m = 0; m < 32; ++m) {
      const float hm0 = h0[m], hm1 = h1[m];
#pragma unroll
      for (int n = 0; n < 32; ++n) {
        const float w = Wl[m * 32 + n];
        a0[n] = fmaf(hm0, w, a0[n]);
        a1[n] = fmaf(hm1, w, a1[n]);
      }
    }
#pragma unroll
    for (int n = 0; n < 32; ++n) {
      h0[n] = fmaxf(a0[n], 0.f);
      h1[n] = fmaxf(a1[n], 0.f);
    }
  }
  float o0 = b_out[0], o1 = b_out[0];
#pragma unroll
  for (int n = 0; n < 32; ++n) {
    const float w = W_out[n];
    o0 = fmaf(h0[n], w, o0);
    o1 = fmaf(h1[n], w, o1);
  }
  float2 r;
  r.x = mk0 ? o0 : 0.0f;
  r.y = mk1 ? o1 : 0.0f;
  *(float2*)(out + base) = r;
}

extern "C" void kernel_launch(void* const* d_in, const int* in_sizes, int n_in,
                              void* d_out, int out_size, void* d_ws, size_t ws_size,
                              hipStream_t stream) {
  const float* Imodel   = (const float*)d_in[0];
  const float* Iobs     = (const float*)d_in[1];
  const float* metadata = (const float*)d_in[2];
  const void*  mask     = d_in[3];
  const int*   sample_size = (const int*)d_in[4];
  const float* W_img_in = (const float*)d_in[5];
  const float* b_img_in = (const float*)d_in[6];
  const float* W_img    = (const float*)d_in[7];
  const float* b_img    = (const float*)d_in[8];
  const float* W_lin_in = (const float*)d_in[9];
  const float* b_lin_in = (const float*)d_in[10];
  const float* W_mlp    = (const float*)d_in[11];
  const float* b_mlp    = (const float*)d_in[12];
  const float* W_out    = (const float*)d_in[13];
  const float* b_out    = (const float*)d_in[14];
  float* out = (float*)d_out;

  char* ws = (char*)d_ws;
  int*   flag     = (int*)(ws + WS_FLAG);
  int*   sel      = (int*)(ws + WS_SEL);
  float* partial  = (float*)(ws + WS_PART);
  float* rep_bias = (float*)(ws + WS_REPB);

  k_prep<<<BB, 256, 0, stream>>>(mask, sample_size, flag, sel);
  k_image<<<BB * 32, 192, 0, stream>>>(Imodel, Iobs, metadata, mask, flag, sel,
                                       sample_size, W_img_in, b_img_in, W_img,
                                       b_img, partial);
  k_rep<<<BB, 32, 0, stream>>>(partial, b_lin_in, rep_bias);
  k_scale<<<3072, 256, 0, stream>>>(metadata, mask, flag, W_lin_in, rep_bias,
                                    W_mlp, b_mlp, W_out, b_out, out);
}

// Round 3
// 236.516 us; speedup vs baseline: 1.3732x; 1.2024x over previous
//
#include <hip/hip_runtime.h>
#include <hip/hip_bf16.h>
#include <stdint.h>

#define BB   16
#define JJ   256
#define KK   384
#define NROW (BB * JJ)               // 4096
#define NPOS ((size_t)BB * JJ * KK)  // 1572864

// ws layout (bytes)
#define WS_FLAG  0
#define WS_SEL   64                          // int[16*32]
#define WS_VINT  2176                        // int[4096]
#define WS_VBYTE (WS_VINT + NROW * 4)        // int[4096]
#define WS_PART  (WS_VBYTE + NROW * 4)       // float[1024][33]
#define WS_REPB  (WS_PART + 1024 * 33 * 4)   // float[16][32]

typedef float f32x4 __attribute__((ext_vector_type(4)));
typedef short bf16x8 __attribute__((ext_vector_type(8)));

__device__ __forceinline__ uint32_t rotl32(uint32_t x, int r) {
  return (x << r) | (x >> (32 - r));
}

__device__ __forceinline__ void threefry2x32_k42(uint32_t c0, uint32_t c1,
                                                 uint32_t& o0, uint32_t& o1) {
  const uint32_t ks0 = 0u, ks1 = 42u, ks2 = 0x1BD11BDAu ^ 0u ^ 42u;
  uint32_t x0 = c0 + ks0, x1 = c1 + ks1;
#define TFR(r) { x0 += x1; x1 = rotl32(x1, r); x1 ^= x0; }
  TFR(13) TFR(15) TFR(26) TFR(6)   x0 += ks1; x1 += ks2 + 1u;
  TFR(17) TFR(29) TFR(16) TFR(24)  x0 += ks2; x1 += ks0 + 2u;
  TFR(13) TFR(15) TFR(26) TFR(6)   x0 += ks0; x1 += ks1 + 3u;
  TFR(17) TFR(29) TFR(16) TFR(24)  x0 += ks1; x1 += ks2 + 4u;
  TFR(13) TFR(15) TFR(26) TFR(6)   x0 += ks2; x1 += ks0 + 5u;
#undef TFR
  o0 = x0; o1 = x1;
}

__device__ __forceinline__ uint32_t jax_bits(uint32_t t) {
  uint32_t o0, o1;
  threefry2x32_k42(0u, t, o0, o1);
  return o0 ^ o1;
}

// split f32 -> hi/lo bf16 (RNE), x ~= hi + lo
__device__ __forceinline__ void split2(float x, short& h, short& l) {
  const unsigned short hu = __builtin_bit_cast(unsigned short, __float2bfloat16(x));
  const float hf = __builtin_bit_cast(float, (uint32_t)hu << 16);
  h = (short)hu;
  l = (short)__builtin_bit_cast(unsigned short, __float2bfloat16(x - hf));
}

// --- 1. row validity under BOTH mask-width interpretations (no flag dep) ---
__global__ __launch_bounds__(256) void k_valid(const void* __restrict__ maskp,
                                               int* __restrict__ valid_int,
                                               int* __restrict__ valid_byte) {
  const int row = blockIdx.x * 4 + (threadIdx.x >> 6);
  const int lane = threadIdx.x & 63;
  // int32-per-element view: row = 384 words
  const uint32_t* wi = (const uint32_t*)maskp + (size_t)row * 384;
  int v = 0;
#pragma unroll
  for (int i = 0; i < 6; ++i) v |= (wi[lane + i * 64] != 0u);
  const unsigned long long bi = __ballot(v);
  // byte-per-element view: row = 384 bytes = 96 words
  const uint32_t* wb = (const uint32_t*)maskp + (size_t)row * 96;
  int u = 0;
  for (int i = lane; i < 96; i += 64) u |= (wb[i] != 0u);
  const unsigned long long bu = __ballot(u);
  if (lane == 0) {
    valid_int[row] = (bi != 0ull) ? 1 : 0;
    valid_byte[row] = (bu != 0ull) ? 1 : 0;
  }
}

// --- 2. detect mask width + per-batch top-S gumbel selection ---
__global__ void k_select(const void* __restrict__ maskp,
                         const int* __restrict__ valid_int,
                         const int* __restrict__ valid_byte,
                         const int* __restrict__ sample_size,
                         int* __restrict__ flag_out, int* __restrict__ sel) {
  const int b = blockIdx.x, lane = threadIdx.x;  // 16 x 64
  const uint32_t* mw = (const uint32_t*)maskp;
  int big = 0;
#pragma unroll
  for (int i = 0; i < 16; ++i) big |= (mw[lane + i * 64] > 1u);
  const int fl = (__ballot(big) != 0ull) ? 1 : 0;
  if (b == 0 && lane == 0) flag_out[0] = fl;
  const int* valid = fl ? valid_byte : valid_int;

  uint32_t comp[4];
#pragma unroll
  for (int q = 0; q < 4; ++q) {
    const int j = lane * 4 + q;
    const uint32_t ub = jax_bits((uint32_t)(b * 256 + j)) >> 9;
    const uint32_t key = valid[b * 256 + j] ? (ub + 1u) : 0u;
    comp[q] = (key << 8) | (uint32_t)(255 - j);  // tie -> smaller j wins
  }
  int S = sample_size[0];
  if (S > 32) S = 32;
  for (int s = 0; s < S; ++s) {
    uint32_t wm = comp[0];
    wm = comp[1] > wm ? comp[1] : wm;
    wm = comp[2] > wm ? comp[2] : wm;
    wm = comp[3] > wm ? comp[3] : wm;
#pragma unroll
    for (int off = 32; off; off >>= 1) {
      const uint32_t o = __shfl_xor(wm, off);
      wm = o > wm ? o : wm;
    }
    if (wm == 0u) {
      if (lane == 0) sel[b * 32 + s] = 0;
    } else {
#pragma unroll
      for (int q = 0; q < 4; ++q) {
        if (comp[q] == wm) {
          sel[b * 32 + s] = 255 - (int)(comp[q] & 0xFFu);
          comp[q] = 0u;
        }
      }
    }
  }
  for (int s2 = S + lane; s2 < 32; s2 += 64) sel[b * 32 + s2] = 0;
}

// --- 3. image branch: 1024 blocks = (b, s, k-half); 192 threads x 1 pos ---
__global__ __launch_bounds__(192) void k_image(
    const float* __restrict__ Imodel, const float* __restrict__ Iobs,
    const float* __restrict__ md, const void* __restrict__ maskp,
    const int* __restrict__ flag, const int* __restrict__ sel,
    const int* __restrict__ sample_size,
    const float* __restrict__ W_in, const float* __restrict__ b_in,
    const float* __restrict__ Wd, const float* __restrict__ bd,
    float* __restrict__ partial) {
  const int blk = blockIdx.x;            // b*64 + s*2 + half
  const int b = blk >> 6, s = (blk >> 1) & 31, half = blk & 1;
  const bool active = (s < sample_size[0]);
  const int j = sel[b * 32 + s] & 255;
  const int k = half * 192 + threadIdx.x;
  const size_t p = ((size_t)(b * JJ + j)) * KK + k;

  float in[8];
  in[0] = Imodel[p];
  in[1] = Iobs[p];
  const float* mp = md + p * 6;
  const float2 v0 = *(const float2*)(mp);
  const float2 v1 = *(const float2*)(mp + 2);
  const float2 v2 = *(const float2*)(mp + 4);
  in[2] = v0.x; in[3] = v0.y; in[4] = v1.x; in[5] = v1.y; in[6] = v2.x; in[7] = v2.y;

  float m;
  if (flag[0]) m = (((const uint8_t*)maskp)[p] != 0) ? 1.f : 0.f;
  else         m = (((const int*)maskp)[p] != 0) ? 1.f : 0.f;
  if (!active) m = 0.f;

  float h[32];
#pragma unroll
  for (int n = 0; n < 32; ++n) {
    float acc = b_in[n];
#pragma unroll
    for (int c = 0; c < 8; ++c) acc = fmaf(in[c], W_in[c * 32 + n], acc);
    h[n] = acc;  // no relu on input layer
  }
#pragma unroll
  for (int d = 0; d < 3; ++d) {
    const float* Wl = Wd + d * 1024;
    const float* bl = bd + d * 32;
    float a[32];
#pragma unroll
    for (int n = 0; n < 32; ++n) a[n] = bl[n];
#pragma unroll
    for (int mm = 0; mm < 32; ++mm) {
      const float hm = h[mm];
#pragma unroll
      for (int n = 0; n < 32; ++n) a[n] = fmaf(hm, Wl[mm * 32 + n], a[n]);
    }
#pragma unroll
    for (int n = 0; n < 32; ++n) h[n] = fmaxf(a[n], 0.f);
  }

  __shared__ float red[3 * 33];
  const int wave = threadIdx.x >> 6, lane = threadIdx.x & 63;
#pragma unroll
  for (int n = 0; n < 32; ++n) {
    float v = h[n] * m;
#pragma unroll
    for (int off = 32; off; off >>= 1) v += __shfl_xor(v, off);
    if (lane == 0) red[wave * 33 + n] = v;
  }
  {
    float v = m;
#pragma unroll
    for (int off = 32; off; off >>= 1) v += __shfl_xor(v, off);
    if (lane == 0) red[wave * 33 + 32] = v;
  }
  __syncthreads();
  if (threadIdx.x < 33) {
    partial[blk * 33 + threadIdx.x] =
        red[threadIdx.x] + red[33 + threadIdx.x] + red[66 + threadIdx.x];
  }
}

// --- 4. reduce partials -> rep_bias[b][n] = b_lin[n] + sum/cnt ---
__global__ void k_rep(const float* __restrict__ partial,
                      const float* __restrict__ b_lin,
                      float* __restrict__ rep_bias) {
  const int b = blockIdx.x, n = threadIdx.x;  // 16 x 32
  float sum = 0.f, cnt = 0.f;
  for (int q = 0; q < 64; ++q) {
    sum += partial[(b * 64 + q) * 33 + n];
    cnt += partial[(b * 64 + q) * 33 + 32];
  }
  rep_bias[b * 32 + n] = b_lin[n] + sum / cnt;
}

// --- 5. main pass: split-bf16 MFMA. wave = 16 tiles x 16 positions ---
// A-frag (16x16x32 bf16): lane l holds A[row=l&15][k=(l>>4)*8+e], e=0..7
// B-frag:                 lane l holds B[k=(l>>4)*8+e][col=l&15]
// C/D    :                lane l reg r: C[row=(l>>4)*4+r][col=l&15]  (m89)
__global__ __launch_bounds__(256, 1) void k_scale(
    const float* __restrict__ md, const void* __restrict__ maskp,
    const int* __restrict__ flag,
    const float* __restrict__ W_lin, const float* __restrict__ rep_bias,
    const float* __restrict__ Wd, const float* __restrict__ bd,
    const float* __restrict__ W_out, const float* __restrict__ b_out,
    float* __restrict__ out) {
  __shared__ float lds_t[4][16 * 36];   // per-wave [pos][feat], stride 36
  const int tid = threadIdx.x;
  const int wid = tid >> 6, lane = tid & 63;
  const int g = lane >> 4, c = lane & 15;
  const int job = blockIdx.x * 4 + wid;       // 6144 jobs x 256 positions
  const int b = job / 384;                    // 384 jobs per batch
  const size_t pos0 = (size_t)job * 256;
  const int fl = flag[0];

  // one-time per-lane fragments
  float Wl[6][8];
#pragma unroll
  for (int cc = 0; cc < 6; ++cc)
#pragma unroll
    for (int e = 0; e < 8; ++e) Wl[cc][e] = W_lin[cc * 32 + g * 8 + e];
  float rbv[8];
#pragma unroll
  for (int e = 0; e < 8; ++e) rbv[e] = rep_bias[b * 32 + g * 8 + e];

  bf16x8 Bh[3][2], Bl[3][2];
#pragma unroll
  for (int d = 0; d < 3; ++d)
#pragma unroll
    for (int ct = 0; ct < 2; ++ct)
#pragma unroll
      for (int e = 0; e < 8; ++e) {
        const float w = Wd[d * 1024 + (g * 8 + e) * 32 + ct * 16 + c];
        short hh, ll; split2(w, hh, ll);
        Bh[d][ct][e] = hh; Bl[d][ct][e] = ll;
      }
  float bias_v[3][2];
#pragma unroll
  for (int d = 0; d < 3; ++d) {
    bias_v[d][0] = bd[d * 32 + c];
    bias_v[d][1] = bd[d * 32 + 16 + c];
  }
  const float w0 = W_out[c], w1 = W_out[16 + c];
  const float bo = b_out[0];
  float* myl = lds_t[wid];

  for (int t = 0; t < 16; ++t) {
    const size_t tb = pos0 + (size_t)t * 16;
    const float* mrow = md + (tb + c) * 6;
    const float2 m01 = *(const float2*)(mrow);
    const float2 m23 = *(const float2*)(mrow + 2);
    const float2 m45 = *(const float2*)(mrow + 4);
    const float mv[6] = {m01.x, m01.y, m23.x, m23.y, m45.x, m45.y};

    // input layer directly in A-fragment layout (pos=c, k=g*8+e)
    bf16x8 ah, al;
#pragma unroll
    for (int e = 0; e < 8; ++e) {
      float h = rbv[e];
#pragma unroll
      for (int cc = 0; cc < 6; ++cc) h = fmaf(mv[cc], Wl[cc][e], h);
      short hh, ll; split2(h, hh, ll);
      ah[e] = hh; al[e] = ll;
    }

#pragma unroll
    for (int d = 0; d < 3; ++d) {
      f32x4 a0 = {0.f, 0.f, 0.f, 0.f}, a1 = {0.f, 0.f, 0.f, 0.f};
      a0 = __builtin_amdgcn_mfma_f32_16x16x32_bf16(ah, Bh[d][0], a0, 0, 0, 0);
      a0 = __builtin_amdgcn_mfma_f32_16x16x32_bf16(al, Bh[d][0], a0, 0, 0, 0);
      a0 = __builtin_amdgcn_mfma_f32_16x16x32_bf16(ah, Bl[d][0], a0, 0, 0, 0);
      a1 = __builtin_amdgcn_mfma_f32_16x16x32_bf16(ah, Bh[d][1], a1, 0, 0, 0);
      a1 = __builtin_amdgcn_mfma_f32_16x16x32_bf16(al, Bh[d][1], a1, 0, 0, 0);
      a1 = __builtin_amdgcn_mfma_f32_16x16x32_bf16(ah, Bl[d][1], a1, 0, 0, 0);
#pragma unroll
      for (int r = 0; r < 4; ++r) {
        a0[r] = fmaxf(a0[r] + bias_v[d][0], 0.f);
        a1[r] = fmaxf(a1[r] + bias_v[d][1], 0.f);
      }
      if (d < 2) {
        // C-layout -> A-layout transpose through wave-private LDS
#pragma unroll
        for (int r = 0; r < 4; ++r) {
          myl[(g * 4 + r) * 36 + c] = a0[r];
          myl[(g * 4 + r) * 36 + 16 + c] = a1[r];
        }
#pragma unroll
        for (int e = 0; e < 8; ++e) {
          const float h = myl[c * 36 + g * 8 + e];
          short hh, ll; split2(h, hh, ll);
          ah[e] = hh; al[e] = ll;
        }
      } else {
        // epilogue: dot with W_out, reduce across the 16 lanes of each group
        float s0 = fmaf(a0[0], w0, a1[0] * w1);
        float s1 = fmaf(a0[1], w0, a1[1] * w1);
        float s2 = fmaf(a0[2], w0, a1[2] * w1);
        float s3 = fmaf(a0[3], w0, a1[3] * w1);
#pragma unroll
        for (int off = 1; off < 16; off <<= 1) {
          s0 += __shfl_xor(s0, off);
          s1 += __shfl_xor(s1, off);
          s2 += __shfl_xor(s2, off);
          s3 += __shfl_xor(s3, off);
        }
        if (c == 0) {
          const size_t pbase = tb + g * 4;
          float4 o;
          if (fl) {
            const uint32_t mw = *(const uint32_t*)((const uint8_t*)maskp + pbase);
            o.x = (mw & 0x000000FFu) ? s0 + bo : 0.f;
            o.y = (mw & 0x0000FF00u) ? s1 + bo : 0.f;
            o.z = (mw & 0x00FF0000u) ? s2 + bo : 0.f;
            o.w = (mw & 0xFF000000u) ? s3 + bo : 0.f;
          } else {
            const int4 mi = *(const int4*)((const int*)maskp + pbase);
            o.x = mi.x ? s0 + bo : 0.f;
            o.y = mi.y ? s1 + bo : 0.f;
            o.z = mi.z ? s2 + bo : 0.f;
            o.w = mi.w ? s3 + bo : 0.f;
          }
          *(float4*)(out + pbase) = o;
        }
      }
    }
  }
}

extern "C" void kernel_launch(void* const* d_in, const int* in_sizes, int n_in,
                              void* d_out, int out_size, void* d_ws, size_t ws_size,
                              hipStream_t stream) {
  const float* Imodel   = (const float*)d_in[0];
  const float* Iobs     = (const float*)d_in[1];
  const float* metadata = (const float*)d_in[2];
  const void*  mask     = d_in[3];
  const int*   sample_size = (const int*)d_in[4];
  const float* W_img_in = (const float*)d_in[5];
  const float* b_img_in = (const float*)d_in[6];
  const float* W_img    = (const float*)d_in[7];
  const float* b_img    = (const float*)d_in[8];
  const float* W_lin_in = (const float*)d_in[9];
  const float* b_lin_in = (const float*)d_in[10];
  const float* W_mlp    = (const float*)d_in[11];
  const float* b_mlp    = (const float*)d_in[12];
  const float* W_out    = (const float*)d_in[13];
  const float* b_out    = (const float*)d_in[14];
  float* out = (float*)d_out;

  char* ws = (char*)d_ws;
  int*   flag     = (int*)(ws + WS_FLAG);
  int*   sel      = (int*)(ws + WS_SEL);
  int*   vint     = (int*)(ws + WS_VINT);
  int*   vbyte    = (int*)(ws + WS_VBYTE);
  float* partial  = (float*)(ws + WS_PART);
  float* rep_bias = (float*)(ws + WS_REPB);

  k_valid<<<NROW / 4, 256, 0, stream>>>(mask, vint, vbyte);
  k_select<<<BB, 64, 0, stream>>>(mask, vint, vbyte, sample_size, flag, sel);
  k_image<<<1024, 192, 0, stream>>>(Imodel, Iobs, metadata, mask, flag, sel,
                                    sample_size, W_img_in, b_img_in, W_img,
                                    b_img, partial);
  k_rep<<<BB, 32, 0, stream>>>(partial, b_lin_in, rep_bias);
  k_scale<<<1536, 256, 0, stream>>>(metadata, mask, flag, W_lin_in, rep_bias,
                                    W_mlp, b_mlp, W_out, b_out, out);
}

// Round 4
// 100.946 us; speedup vs baseline: 3.2174x; 2.3430x over previous
//
#include <hip/hip_runtime.h>
#include <hip/hip_bf16.h>
#include <stdint.h>

#define BB   16
#define JJ   256
#define KK   384
#define NROW (BB * JJ)               // 4096
#define NPOS ((size_t)BB * JJ * KK)  // 1572864

// ws layout (bytes)
#define WS_FLAG  0
#define WS_SEL   64                          // int[16*32]
#define WS_VINT  2176                        // int[4096]
#define WS_VBYTE (WS_VINT + NROW * 4)        // int[4096]
#define WS_PART  (WS_VBYTE + NROW * 4)       // float[512][33]
#define WS_REPB  (WS_PART + 512 * 33 * 4)    // float[16][32]

typedef float f32x4 __attribute__((ext_vector_type(4)));
typedef short bf16x8 __attribute__((ext_vector_type(8)));

__device__ __forceinline__ uint32_t rotl32(uint32_t x, int r) {
  return (x << r) | (x >> (32 - r));
}

__device__ __forceinline__ void threefry2x32_k42(uint32_t c0, uint32_t c1,
                                                 uint32_t& o0, uint32_t& o1) {
  const uint32_t ks0 = 0u, ks1 = 42u, ks2 = 0x1BD11BDAu ^ 0u ^ 42u;
  uint32_t x0 = c0 + ks0, x1 = c1 + ks1;
#define TFR(r) { x0 += x1; x1 = rotl32(x1, r); x1 ^= x0; }
  TFR(13) TFR(15) TFR(26) TFR(6)   x0 += ks1; x1 += ks2 + 1u;
  TFR(17) TFR(29) TFR(16) TFR(24)  x0 += ks2; x1 += ks0 + 2u;
  TFR(13) TFR(15) TFR(26) TFR(6)   x0 += ks0; x1 += ks1 + 3u;
  TFR(17) TFR(29) TFR(16) TFR(24)  x0 += ks1; x1 += ks2 + 4u;
  TFR(13) TFR(15) TFR(26) TFR(6)   x0 += ks2; x1 += ks0 + 5u;
#undef TFR
  o0 = x0; o1 = x1;
}

__device__ __forceinline__ uint32_t jax_bits(uint32_t t) {
  uint32_t o0, o1;
  threefry2x32_k42(0u, t, o0, o1);
  return o0 ^ o1;
}

// split f32 -> hi/lo bf16 (RNE), x ~= hi + lo
__device__ __forceinline__ void split2(float x, short& h, short& l) {
  const unsigned short hu = __builtin_bit_cast(unsigned short, __float2bfloat16(x));
  const float hf = __builtin_bit_cast(float, (uint32_t)hu << 16);
  h = (short)hu;
  l = (short)__builtin_bit_cast(unsigned short, __float2bfloat16(x - hf));
}

// --- 1. row validity under BOTH mask-width interpretations ---
__global__ __launch_bounds__(256) void k_valid(const void* __restrict__ maskp,
                                               int* __restrict__ valid_int,
                                               int* __restrict__ valid_byte) {
  const int row = blockIdx.x * 4 + (threadIdx.x >> 6);
  const int lane = threadIdx.x & 63;
  const uint32_t* wi = (const uint32_t*)maskp + (size_t)row * 384;
  int v = 0;
#pragma unroll
  for (int i = 0; i < 6; ++i) v |= (wi[lane + i * 64] != 0u);
  const unsigned long long bi = __ballot(v);
  const uint32_t* wb = (const uint32_t*)maskp + (size_t)row * 96;
  int u = 0;
  for (int i = lane; i < 96; i += 64) u |= (wb[i] != 0u);
  const unsigned long long bu = __ballot(u);
  if (lane == 0) {
    valid_int[row] = (bi != 0ull) ? 1 : 0;
    valid_byte[row] = (bu != 0ull) ? 1 : 0;
  }
}

// --- 2. detect mask width + per-batch top-S gumbel selection ---
__global__ void k_select(const void* __restrict__ maskp,
                         const int* __restrict__ valid_int,
                         const int* __restrict__ valid_byte,
                         const int* __restrict__ sample_size,
                         int* __restrict__ flag_out, int* __restrict__ sel) {
  const int b = blockIdx.x, lane = threadIdx.x;  // 16 x 64
  const uint32_t* mw = (const uint32_t*)maskp;
  int big = 0;
#pragma unroll
  for (int i = 0; i < 16; ++i) big |= (mw[lane + i * 64] > 1u);
  const int fl = (__ballot(big) != 0ull) ? 1 : 0;
  if (b == 0 && lane == 0) flag_out[0] = fl;
  const int* valid = fl ? valid_byte : valid_int;

  uint32_t comp[4];
#pragma unroll
  for (int q = 0; q < 4; ++q) {
    const int j = lane * 4 + q;
    const uint32_t ub = jax_bits((uint32_t)(b * 256 + j)) >> 9;
    const uint32_t key = valid[b * 256 + j] ? (ub + 1u) : 0u;
    comp[q] = (key << 8) | (uint32_t)(255 - j);  // tie -> smaller j wins
  }
  int S = sample_size[0];
  if (S > 32) S = 32;
  for (int s = 0; s < S; ++s) {
    uint32_t wm = comp[0];
    wm = comp[1] > wm ? comp[1] : wm;
    wm = comp[2] > wm ? comp[2] : wm;
    wm = comp[3] > wm ? comp[3] : wm;
#pragma unroll
    for (int off = 32; off; off >>= 1) {
      const uint32_t o = __shfl_xor(wm, off);
      wm = o > wm ? o : wm;
    }
    if (wm == 0u) {
      if (lane == 0) sel[b * 32 + s] = 0;
    } else {
#pragma unroll
      for (int q = 0; q < 4; ++q) {
        if (comp[q] == wm) {
          sel[b * 32 + s] = 255 - (int)(comp[q] & 0xFFu);
          comp[q] = 0u;
        }
      }
    }
  }
  for (int s2 = S + lane; s2 < 32; s2 += 64) sel[b * 32 + s2] = 0;
}

// --- 3. image branch via split-bf16 MFMA ---
// block = one (b,s); 4 waves x 6 tiles x 16 positions = 384 = KK
// A-frag: lane l holds A[row=l&15][k=(l>>4)*8+e]; C/D: row=(l>>4)*4+r, col=l&15
__global__ __launch_bounds__(256, 1) void k_image(
    const float* __restrict__ Imodel, const float* __restrict__ Iobs,
    const float* __restrict__ md, const void* __restrict__ maskp,
    const int* __restrict__ flag, const int* __restrict__ sel,
    const int* __restrict__ sample_size,
    const float* __restrict__ W_in, const float* __restrict__ b_in,
    const float* __restrict__ Wd, const float* __restrict__ bd,
    float* __restrict__ partial) {
  __shared__ float lds_t[4][16 * 36];
  __shared__ float red[4 * 33];
  const int tid = threadIdx.x, wid = tid >> 6, lane = tid & 63;
  const int g = lane >> 4, c = lane & 15;
  const int blk = blockIdx.x;   // 512 = b*32 + s
  const int b = blk >> 5, s = blk & 31;
  const bool active = (s < sample_size[0]);
  const int j = sel[b * 32 + s] & 255;
  const size_t pos0 = ((size_t)(b * JJ + j)) * KK + (size_t)wid * 96;
  const int fl = flag[0];

  // per-lane fragments (k = g*8+e)
  float Win[8][8];
#pragma unroll
  for (int cc = 0; cc < 8; ++cc)
#pragma unroll
    for (int e = 0; e < 8; ++e) Win[cc][e] = W_in[cc * 32 + g * 8 + e];
  float b0v[8];
#pragma unroll
  for (int e = 0; e < 8; ++e) b0v[e] = b_in[g * 8 + e];

  bf16x8 Bh[3][2], Bl[3][2];
#pragma unroll
  for (int d = 0; d < 3; ++d)
#pragma unroll
    for (int ct = 0; ct < 2; ++ct)
#pragma unroll
      for (int e = 0; e < 8; ++e) {
        const float w = Wd[d * 1024 + (g * 8 + e) * 32 + ct * 16 + c];
        short hh, ll; split2(w, hh, ll);
        Bh[d][ct][e] = hh; Bl[d][ct][e] = ll;
      }
  float bias_v[3][2];
#pragma unroll
  for (int d = 0; d < 3; ++d) {
    bias_v[d][0] = bd[d * 32 + c];
    bias_v[d][1] = bd[d * 32 + 16 + c];
  }
  float* myl = lds_t[wid];

  float acc0 = 0.f, acc1 = 0.f, cntv = 0.f;

  for (int t = 0; t < 6; ++t) {
    const size_t tb = pos0 + (size_t)t * 16;
    const size_t p = tb + c;
    float in[8];
    in[0] = Imodel[p];
    in[1] = Iobs[p];
    const float* mp = md + p * 6;
    const float2 v0 = *(const float2*)(mp);
    const float2 v1 = *(const float2*)(mp + 2);
    const float2 v2 = *(const float2*)(mp + 4);
    in[2] = v0.x; in[3] = v0.y; in[4] = v1.x; in[5] = v1.y;
    in[6] = v2.x; in[7] = v2.y;

    // input layer directly in A-fragment layout (pos=c, feat=g*8+e)
    bf16x8 ah, al;
#pragma unroll
    for (int e = 0; e < 8; ++e) {
      float h = b0v[e];
#pragma unroll
      for (int cc = 0; cc < 8; ++cc) h = fmaf(in[cc], Win[cc][e], h);
      short hh, ll; split2(h, hh, ll);
      ah[e] = hh; al[e] = ll;
    }

#pragma unroll
    for (int d = 0; d < 3; ++d) {
      f32x4 a0 = {0.f, 0.f, 0.f, 0.f}, a1 = {0.f, 0.f, 0.f, 0.f};
      a0 = __builtin_amdgcn_mfma_f32_16x16x32_bf16(ah, Bh[d][0], a0, 0, 0, 0);
      a0 = __builtin_amdgcn_mfma_f32_16x16x32_bf16(al, Bh[d][0], a0, 0, 0, 0);
      a0 = __builtin_amdgcn_mfma_f32_16x16x32_bf16(ah, Bl[d][0], a0, 0, 0, 0);
      a1 = __builtin_amdgcn_mfma_f32_16x16x32_bf16(ah, Bh[d][1], a1, 0, 0, 0);
      a1 = __builtin_amdgcn_mfma_f32_16x16x32_bf16(al, Bh[d][1], a1, 0, 0, 0);
      a1 = __builtin_amdgcn_mfma_f32_16x16x32_bf16(ah, Bl[d][1], a1, 0, 0, 0);
#pragma unroll
      for (int r = 0; r < 4; ++r) {
        a0[r] = fmaxf(a0[r] + bias_v[d][0], 0.f);
        a1[r] = fmaxf(a1[r] + bias_v[d][1], 0.f);
      }
      if (d < 2) {
#pragma unroll
        for (int r = 0; r < 4; ++r) {
          myl[(g * 4 + r) * 36 + c] = a0[r];
          myl[(g * 4 + r) * 36 + 16 + c] = a1[r];
        }
#pragma unroll
        for (int e = 0; e < 8; ++e) {
          const float h = myl[c * 36 + g * 8 + e];
          short hh, ll; split2(h, hh, ll);
          ah[e] = hh; al[e] = ll;
        }
      } else {
        // masked accumulate: lane handles rows g*4+r (positions tb+g*4+r)
        float mr[4];
        if (fl) {
          const uint32_t mw = *(const uint32_t*)((const uint8_t*)maskp + tb + g * 4);
          mr[0] = (mw & 0x000000FFu) ? 1.f : 0.f;
          mr[1] = (mw & 0x0000FF00u) ? 1.f : 0.f;
          mr[2] = (mw & 0x00FF0000u) ? 1.f : 0.f;
          mr[3] = (mw & 0xFF000000u) ? 1.f : 0.f;
        } else {
          const int4 mi = *(const int4*)((const int*)maskp + tb + g * 4);
          mr[0] = mi.x ? 1.f : 0.f;
          mr[1] = mi.y ? 1.f : 0.f;
          mr[2] = mi.z ? 1.f : 0.f;
          mr[3] = mi.w ? 1.f : 0.f;
        }
        if (!active) { mr[0] = mr[1] = mr[2] = mr[3] = 0.f; }
#pragma unroll
        for (int r = 0; r < 4; ++r) {
          acc0 = fmaf(mr[r], a0[r], acc0);
          acc1 = fmaf(mr[r], a1[r], acc1);
          cntv += mr[r];
        }
      }
    }
  }

  // reduce over g (lanes with same c, different g hold different rows)
  acc0 += __shfl_xor(acc0, 16); acc0 += __shfl_xor(acc0, 32);
  acc1 += __shfl_xor(acc1, 16); acc1 += __shfl_xor(acc1, 32);
  cntv += __shfl_xor(cntv, 16); cntv += __shfl_xor(cntv, 32);
  if (lane < 16) {
    red[wid * 33 + lane] = acc0;
    red[wid * 33 + 16 + lane] = acc1;
  }
  if (lane == 0) red[wid * 33 + 32] = cntv;
  __syncthreads();
  if (tid < 33) {
    partial[blk * 33 + tid] =
        red[tid] + red[33 + tid] + red[66 + tid] + red[99 + tid];
  }
}

// --- 4. reduce partials -> rep_bias[b][n] = b_lin[n] + sum/cnt ---
__global__ void k_rep(const float* __restrict__ partial,
                      const float* __restrict__ b_lin,
                      float* __restrict__ rep_bias) {
  const int b = blockIdx.x, n = threadIdx.x;  // 16 x 32
  float sum = 0.f, cnt = 0.f;
  for (int s = 0; s < 32; ++s) {
    sum += partial[(b * 32 + s) * 33 + n];
    cnt += partial[(b * 32 + s) * 33 + 32];
  }
  rep_bias[b * 32 + n] = b_lin[n] + sum / cnt;
}

// --- 5. main pass: split-bf16 MFMA (unchanged from R3) ---
__global__ __launch_bounds__(256, 1) void k_scale(
    const float* __restrict__ md, const void* __restrict__ maskp,
    const int* __restrict__ flag,
    const float* __restrict__ W_lin, const float* __restrict__ rep_bias,
    const float* __restrict__ Wd, const float* __restrict__ bd,
    const float* __restrict__ W_out, const float* __restrict__ b_out,
    float* __restrict__ out) {
  __shared__ float lds_t[4][16 * 36];
  const int tid = threadIdx.x;
  const int wid = tid >> 6, lane = tid & 63;
  const int g = lane >> 4, c = lane & 15;
  const int job = blockIdx.x * 4 + wid;       // 6144 jobs x 256 positions
  const int b = job / 384;
  const size_t pos0 = (size_t)job * 256;
  const int fl = flag[0];

  float Wl[6][8];
#pragma unroll
  for (int cc = 0; cc < 6; ++cc)
#pragma unroll
    for (int e = 0; e < 8; ++e) Wl[cc][e] = W_lin[cc * 32 + g * 8 + e];
  float rbv[8];
#pragma unroll
  for (int e = 0; e < 8; ++e) rbv[e] = rep_bias[b * 32 + g * 8 + e];

  bf16x8 Bh[3][2], Bl[3][2];
#pragma unroll
  for (int d = 0; d < 3; ++d)
#pragma unroll
    for (int ct = 0; ct < 2; ++ct)
#pragma unroll
      for (int e = 0; e < 8; ++e) {
        const float w = Wd[d * 1024 + (g * 8 + e) * 32 + ct * 16 + c];
        short hh, ll; split2(w, hh, ll);
        Bh[d][ct][e] = hh; Bl[d][ct][e] = ll;
      }
  float bias_v[3][2];
#pragma unroll
  for (int d = 0; d < 3; ++d) {
    bias_v[d][0] = bd[d * 32 + c];
    bias_v[d][1] = bd[d * 32 + 16 + c];
  }
  const float w0 = W_out[c], w1 = W_out[16 + c];
  const float bo = b_out[0];
  float* myl = lds_t[wid];

  for (int t = 0; t < 16; ++t) {
    const size_t tb = pos0 + (size_t)t * 16;
    const float* mrow = md + (tb + c) * 6;
    const float2 m01 = *(const float2*)(mrow);
    const float2 m23 = *(const float2*)(mrow + 2);
    const float2 m45 = *(const float2*)(mrow + 4);
    const float mv[6] = {m01.x, m01.y, m23.x, m23.y, m45.x, m45.y};

    bf16x8 ah, al;
#pragma unroll
    for (int e = 0; e < 8; ++e) {
      float h = rbv[e];
#pragma unroll
      for (int cc = 0; cc < 6; ++cc) h = fmaf(mv[cc], Wl[cc][e], h);
      short hh, ll; split2(h, hh, ll);
      ah[e] = hh; al[e] = ll;
    }

#pragma unroll
    for (int d = 0; d < 3; ++d) {
      f32x4 a0 = {0.f, 0.f, 0.f, 0.f}, a1 = {0.f, 0.f, 0.f, 0.f};
      a0 = __builtin_amdgcn_mfma_f32_16x16x32_bf16(ah, Bh[d][0], a0, 0, 0, 0);
      a0 = __builtin_amdgcn_mfma_f32_16x16x32_bf16(al, Bh[d][0], a0, 0, 0, 0);
      a0 = __builtin_amdgcn_mfma_f32_16x16x32_bf16(ah, Bl[d][0], a0, 0, 0, 0);
      a1 = __builtin_amdgcn_mfma_f32_16x16x32_bf16(ah, Bh[d][1], a1, 0, 0, 0);
      a1 = __builtin_amdgcn_mfma_f32_16x16x32_bf16(al, Bh[d][1], a1, 0, 0, 0);
      a1 = __builtin_amdgcn_mfma_f32_16x16x32_bf16(ah, Bl[d][1], a1, 0, 0, 0);
#pragma unroll
      for (int r = 0; r < 4; ++r) {
        a0[r] = fmaxf(a0[r] + bias_v[d][0], 0.f);
        a1[r] = fmaxf(a1[r] + bias_v[d][1], 0.f);
      }
      if (d < 2) {
#pragma unroll
        for (int r = 0; r < 4; ++r) {
          myl[(g * 4 + r) * 36 + c] = a0[r];
          myl[(g * 4 + r) * 36 + 16 + c] = a1[r];
        }
#pragma unroll
        for (int e = 0; e < 8; ++e) {
          const float h = myl[c * 36 + g * 8 + e];
          short hh, ll; split2(h, hh, ll);
          ah[e] = hh; al[e] = ll;
        }
      } else {
        float s0 = fmaf(a0[0], w0, a1[0] * w1);
        float s1 = fmaf(a0[1], w0, a1[1] * w1);
        float s2 = fmaf(a0[2], w0, a1[2] * w1);
        float s3 = fmaf(a0[3], w0, a1[3] * w1);
#pragma unroll
        for (int off = 1; off < 16; off <<= 1) {
          s0 += __shfl_xor(s0, off);
          s1 += __shfl_xor(s1, off);
          s2 += __shfl_xor(s2, off);
          s3 += __shfl_xor(s3, off);
        }
        if (c == 0) {
          const size_t pbase = tb + g * 4;
          float4 o;
          if (fl) {
            const uint32_t mw = *(const uint32_t*)((const uint8_t*)maskp + pbase);
            o.x = (mw & 0x000000FFu) ? s0 + bo : 0.f;
            o.y = (mw & 0x0000FF00u) ? s1 + bo : 0.f;
            o.z = (mw & 0x00FF0000u) ? s2 + bo : 0.f;
            o.w = (mw & 0xFF000000u) ? s3 + bo : 0.f;
          } else {
            const int4 mi = *(const int4*)((const int*)maskp + pbase);
            o.x = mi.x ? s0 + bo : 0.f;
            o.y = mi.y ? s1 + bo : 0.f;
            o.z = mi.z ? s2 + bo : 0.f;
            o.w = mi.w ? s3 + bo : 0.f;
          }
          *(float4*)(out + pbase) = o;
        }
      }
    }
  }
}

extern "C" void kernel_launch(void* const* d_in, const int* in_sizes, int n_in,
                              void* d_out, int out_size, void* d_ws, size_t ws_size,
                              hipStream_t stream) {
  const float* Imodel   = (const float*)d_in[0];
  const float* Iobs     = (const float*)d_in[1];
  const float* metadata = (const float*)d_in[2];
  const void*  mask     = d_in[3];
  const int*   sample_size = (const int*)d_in[4];
  const float* W_img_in = (const float*)d_in[5];
  const float* b_img_in = (const float*)d_in[6];
  const float* W_img    = (const float*)d_in[7];
  const float* b_img    = (const float*)d_in[8];
  const float* W_lin_in = (const float*)d_in[9];
  const float* b_lin_in = (const float*)d_in[10];
  const float* W_mlp    = (const float*)d_in[11];
  const float* b_mlp    = (const float*)d_in[12];
  const float* W_out    = (const float*)d_in[13];
  const float* b_out    = (const float*)d_in[14];
  float* out = (float*)d_out;

  char* ws = (char*)d_ws;
  int*   flag     = (int*)(ws + WS_FLAG);
  int*   sel      = (int*)(ws + WS_SEL);
  int*   vint     = (int*)(ws + WS_VINT);
  int*   vbyte    = (int*)(ws + WS_VBYTE);
  float* partial  = (float*)(ws + WS_PART);
  float* rep_bias = (float*)(ws + WS_REPB);

  k_valid<<<NROW / 4, 256, 0, stream>>>(mask, vint, vbyte);
  k_select<<<BB, 64, 0, stream>>>(mask, vint, vbyte, sample_size, flag, sel);
  k_image<<<512, 256, 0, stream>>>(Imodel, Iobs, metadata, mask, flag, sel,
                                   sample_size, W_img_in, b_img_in, W_img,
                                   b_img, partial);
  k_rep<<<BB, 32, 0, stream>>>(partial, b_lin_in, rep_bias);
  k_scale<<<1536, 256, 0, stream>>>(metadata, mask, flag, W_lin_in, rep_bias,
                                    W_mlp, b_mlp, W_out, b_out, out);
}

// Round 5
// 97.726 us; speedup vs baseline: 3.3234x; 1.0330x over previous
//
#include <hip/hip_runtime.h>
#include <hip/hip_bf16.h>
#include <stdint.h>

#define BB   16
#define JJ   256
#define KK   384
#define NROW (BB * JJ)               // 4096
#define NPOS ((size_t)BB * JJ * KK)  // 1572864

// ws layout (bytes)
#define WS_FLAG  0
#define WS_SEL   64                          // int[16*32]
#define WS_VINT  2176                        // int[4096]
#define WS_VBYTE (WS_VINT + NROW * 4)        // int[4096]
#define WS_PART  (WS_VBYTE + NROW * 4)       // float[512][33]
#define WS_REPB  (WS_PART + 512 * 33 * 4)    // float[16][32]

typedef float f32x4 __attribute__((ext_vector_type(4)));
typedef short bf16x8 __attribute__((ext_vector_type(8)));

__device__ __forceinline__ uint32_t rotl32(uint32_t x, int r) {
  return (x << r) | (x >> (32 - r));
}

__device__ __forceinline__ void threefry2x32_k42(uint32_t c0, uint32_t c1,
                                                 uint32_t& o0, uint32_t& o1) {
  const uint32_t ks0 = 0u, ks1 = 42u, ks2 = 0x1BD11BDAu ^ 0u ^ 42u;
  uint32_t x0 = c0 + ks0, x1 = c1 + ks1;
#define TFR(r) { x0 += x1; x1 = rotl32(x1, r); x1 ^= x0; }
  TFR(13) TFR(15) TFR(26) TFR(6)   x0 += ks1; x1 += ks2 + 1u;
  TFR(17) TFR(29) TFR(16) TFR(24)  x0 += ks2; x1 += ks0 + 2u;
  TFR(13) TFR(15) TFR(26) TFR(6)   x0 += ks0; x1 += ks1 + 3u;
  TFR(17) TFR(29) TFR(16) TFR(24)  x0 += ks1; x1 += ks2 + 4u;
  TFR(13) TFR(15) TFR(26) TFR(6)   x0 += ks2; x1 += ks0 + 5u;
#undef TFR
  o0 = x0; o1 = x1;
}

__device__ __forceinline__ uint32_t jax_bits(uint32_t t) {
  uint32_t o0, o1;
  threefry2x32_k42(0u, t, o0, o1);
  return o0 ^ o1;
}

// split f32 -> hi/lo bf16 (RNE), x ~= hi + lo
__device__ __forceinline__ void split2(float x, short& h, short& l) {
  const unsigned short hu = __builtin_bit_cast(unsigned short, __float2bfloat16(x));
  const float hf = __builtin_bit_cast(float, (uint32_t)hu << 16);
  h = (short)hu;
  l = (short)__builtin_bit_cast(unsigned short, __float2bfloat16(x - hf));
}

// --- 1. row validity under BOTH mask-width interpretations ---
__global__ __launch_bounds__(256) void k_valid(const void* __restrict__ maskp,
                                               int* __restrict__ valid_int,
                                               int* __restrict__ valid_byte) {
  const int row = blockIdx.x * 4 + (threadIdx.x >> 6);
  const int lane = threadIdx.x & 63;
  const uint32_t* wi = (const uint32_t*)maskp + (size_t)row * 384;
  int v = 0;
#pragma unroll
  for (int i = 0; i < 6; ++i) v |= (wi[lane + i * 64] != 0u);
  const unsigned long long bi = __ballot(v);
  const uint32_t* wb = (const uint32_t*)maskp + (size_t)row * 96;
  int u = 0;
  for (int i = lane; i < 96; i += 64) u |= (wb[i] != 0u);
  const unsigned long long bu = __ballot(u);
  if (lane == 0) {
    valid_int[row] = (bi != 0ull) ? 1 : 0;
    valid_byte[row] = (bu != 0ull) ? 1 : 0;
  }
}

// --- 2. detect mask width + per-batch top-S gumbel selection ---
__global__ void k_select(const void* __restrict__ maskp,
                         const int* __restrict__ valid_int,
                         const int* __restrict__ valid_byte,
                         const int* __restrict__ sample_size,
                         int* __restrict__ flag_out, int* __restrict__ sel) {
  const int b = blockIdx.x, lane = threadIdx.x;  // 16 x 64
  const uint32_t* mw = (const uint32_t*)maskp;
  int big = 0;
#pragma unroll
  for (int i = 0; i < 16; ++i) big |= (mw[lane + i * 64] > 1u);
  const int fl = (__ballot(big) != 0ull) ? 1 : 0;
  if (b == 0 && lane == 0) flag_out[0] = fl;
  const int* valid = fl ? valid_byte : valid_int;

  uint32_t comp[4];
#pragma unroll
  for (int q = 0; q < 4; ++q) {
    const int j = lane * 4 + q;
    const uint32_t ub = jax_bits((uint32_t)(b * 256 + j)) >> 9;
    const uint32_t key = valid[b * 256 + j] ? (ub + 1u) : 0u;
    comp[q] = (key << 8) | (uint32_t)(255 - j);  // tie -> smaller j wins
  }
  int S = sample_size[0];
  if (S > 32) S = 32;
  for (int s = 0; s < S; ++s) {
    uint32_t wm = comp[0];
    wm = comp[1] > wm ? comp[1] : wm;
    wm = comp[2] > wm ? comp[2] : wm;
    wm = comp[3] > wm ? comp[3] : wm;
#pragma unroll
    for (int off = 32; off; off >>= 1) {
      const uint32_t o = __shfl_xor(wm, off);
      wm = o > wm ? o : wm;
    }
    if (wm == 0u) {
      if (lane == 0) sel[b * 32 + s] = 0;
    } else {
#pragma unroll
      for (int q = 0; q < 4; ++q) {
        if (comp[q] == wm) {
          sel[b * 32 + s] = 255 - (int)(comp[q] & 0xFFu);
          comp[q] = 0u;
        }
      }
    }
  }
  for (int s2 = S + lane; s2 < 32; s2 += 64) sel[b * 32 + s2] = 0;
}

// --- 3. image branch via split-bf16 MFMA (unchanged from R4) ---
__global__ __launch_bounds__(256, 1) void k_image(
    const float* __restrict__ Imodel, const float* __restrict__ Iobs,
    const float* __restrict__ md, const void* __restrict__ maskp,
    const int* __restrict__ flag, const int* __restrict__ sel,
    const int* __restrict__ sample_size,
    const float* __restrict__ W_in, const float* __restrict__ b_in,
    const float* __restrict__ Wd, const float* __restrict__ bd,
    float* __restrict__ partial) {
  __shared__ float lds_t[4][16 * 36];
  __shared__ float red[4 * 33];
  const int tid = threadIdx.x, wid = tid >> 6, lane = tid & 63;
  const int g = lane >> 4, c = lane & 15;
  const int blk = blockIdx.x;   // 512 = b*32 + s
  const int b = blk >> 5, s = blk & 31;
  const bool active = (s < sample_size[0]);
  const int j = sel[b * 32 + s] & 255;
  const size_t pos0 = ((size_t)(b * JJ + j)) * KK + (size_t)wid * 96;
  const int fl = flag[0];

  float Win[8][8];
#pragma unroll
  for (int cc = 0; cc < 8; ++cc)
#pragma unroll
    for (int e = 0; e < 8; ++e) Win[cc][e] = W_in[cc * 32 + g * 8 + e];
  float b0v[8];
#pragma unroll
  for (int e = 0; e < 8; ++e) b0v[e] = b_in[g * 8 + e];

  bf16x8 Bh[3][2], Bl[3][2];
#pragma unroll
  for (int d = 0; d < 3; ++d)
#pragma unroll
    for (int ct = 0; ct < 2; ++ct)
#pragma unroll
      for (int e = 0; e < 8; ++e) {
        const float w = Wd[d * 1024 + (g * 8 + e) * 32 + ct * 16 + c];
        short hh, ll; split2(w, hh, ll);
        Bh[d][ct][e] = hh; Bl[d][ct][e] = ll;
      }
  float bias_v[3][2];
#pragma unroll
  for (int d = 0; d < 3; ++d) {
    bias_v[d][0] = bd[d * 32 + c];
    bias_v[d][1] = bd[d * 32 + 16 + c];
  }
  float* myl = lds_t[wid];

  float acc0 = 0.f, acc1 = 0.f, cntv = 0.f;

  for (int t = 0; t < 6; ++t) {
    const size_t tb = pos0 + (size_t)t * 16;
    const size_t p = tb + c;
    float in[8];
    in[0] = Imodel[p];
    in[1] = Iobs[p];
    const float* mp = md + p * 6;
    const float2 v0 = *(const float2*)(mp);
    const float2 v1 = *(const float2*)(mp + 2);
    const float2 v2 = *(const float2*)(mp + 4);
    in[2] = v0.x; in[3] = v0.y; in[4] = v1.x; in[5] = v1.y;
    in[6] = v2.x; in[7] = v2.y;

    bf16x8 ah, al;
#pragma unroll
    for (int e = 0; e < 8; ++e) {
      float h = b0v[e];
#pragma unroll
      for (int cc = 0; cc < 8; ++cc) h = fmaf(in[cc], Win[cc][e], h);
      short hh, ll; split2(h, hh, ll);
      ah[e] = hh; al[e] = ll;
    }

#pragma unroll
    for (int d = 0; d < 3; ++d) {
      f32x4 a0 = {0.f, 0.f, 0.f, 0.f}, a1 = {0.f, 0.f, 0.f, 0.f};
      a0 = __builtin_amdgcn_mfma_f32_16x16x32_bf16(ah, Bh[d][0], a0, 0, 0, 0);
      a0 = __builtin_amdgcn_mfma_f32_16x16x32_bf16(al, Bh[d][0], a0, 0, 0, 0);
      a0 = __builtin_amdgcn_mfma_f32_16x16x32_bf16(ah, Bl[d][0], a0, 0, 0, 0);
      a1 = __builtin_amdgcn_mfma_f32_16x16x32_bf16(ah, Bh[d][1], a1, 0, 0, 0);
      a1 = __builtin_amdgcn_mfma_f32_16x16x32_bf16(al, Bh[d][1], a1, 0, 0, 0);
      a1 = __builtin_amdgcn_mfma_f32_16x16x32_bf16(ah, Bl[d][1], a1, 0, 0, 0);
#pragma unroll
      for (int r = 0; r < 4; ++r) {
        a0[r] = fmaxf(a0[r] + bias_v[d][0], 0.f);
        a1[r] = fmaxf(a1[r] + bias_v[d][1], 0.f);
      }
      if (d < 2) {
#pragma unroll
        for (int r = 0; r < 4; ++r) {
          myl[(g * 4 + r) * 36 + c] = a0[r];
          myl[(g * 4 + r) * 36 + 16 + c] = a1[r];
        }
#pragma unroll
        for (int e = 0; e < 8; ++e) {
          const float h = myl[c * 36 + g * 8 + e];
          short hh, ll; split2(h, hh, ll);
          ah[e] = hh; al[e] = ll;
        }
      } else {
        float mr[4];
        if (fl) {
          const uint32_t mw = *(const uint32_t*)((const uint8_t*)maskp + tb + g * 4);
          mr[0] = (mw & 0x000000FFu) ? 1.f : 0.f;
          mr[1] = (mw & 0x0000FF00u) ? 1.f : 0.f;
          mr[2] = (mw & 0x00FF0000u) ? 1.f : 0.f;
          mr[3] = (mw & 0xFF000000u) ? 1.f : 0.f;
        } else {
          const int4 mi = *(const int4*)((const int*)maskp + tb + g * 4);
          mr[0] = mi.x ? 1.f : 0.f;
          mr[1] = mi.y ? 1.f : 0.f;
          mr[2] = mi.z ? 1.f : 0.f;
          mr[3] = mi.w ? 1.f : 0.f;
        }
        if (!active) { mr[0] = mr[1] = mr[2] = mr[3] = 0.f; }
#pragma unroll
        for (int r = 0; r < 4; ++r) {
          acc0 = fmaf(mr[r], a0[r], acc0);
          acc1 = fmaf(mr[r], a1[r], acc1);
          cntv += mr[r];
        }
      }
    }
  }

  acc0 += __shfl_xor(acc0, 16); acc0 += __shfl_xor(acc0, 32);
  acc1 += __shfl_xor(acc1, 16); acc1 += __shfl_xor(acc1, 32);
  cntv += __shfl_xor(cntv, 16); cntv += __shfl_xor(cntv, 32);
  if (lane < 16) {
    red[wid * 33 + lane] = acc0;
    red[wid * 33 + 16 + lane] = acc1;
  }
  if (lane == 0) red[wid * 33 + 32] = cntv;
  __syncthreads();
  if (tid < 33) {
    partial[blk * 33 + tid] =
        red[tid] + red[33 + tid] + red[66 + tid] + red[99 + tid];
  }
}

// --- 4. reduce partials -> rep_bias[b][n] = b_lin[n] + sum/cnt ---
__global__ void k_rep(const float* __restrict__ partial,
                      const float* __restrict__ b_lin,
                      float* __restrict__ rep_bias) {
  const int b = blockIdx.x, n = threadIdx.x;  // 16 x 32
  float sum = 0.f, cnt = 0.f;
  for (int s = 0; s < 32; ++s) {
    sum += partial[(b * 32 + s) * 33 + n];
    cnt += partial[(b * 32 + s) * 33 + 32];
  }
  rep_bias[b * 32 + n] = b_lin[n] + sum / cnt;
}

// --- 5. main pass: all-MFMA (input layer folded into MFMA, bias in k=6) ---
// A-frag: lane l=(g,c) holds A[row=c][k=g*8+e]; C/D: row=(l>>4)*4+r, col=l&15
__global__ __launch_bounds__(256, 1) void k_scale(
    const float* __restrict__ md, const void* __restrict__ maskp,
    const int* __restrict__ flag,
    const float* __restrict__ W_lin, const float* __restrict__ rep_bias,
    const float* __restrict__ Wd, const float* __restrict__ bd,
    const float* __restrict__ W_out, const float* __restrict__ b_out,
    float* __restrict__ out) {
  __shared__ float ldsA[4][16 * 36];
  __shared__ float ldsB[4][16 * 36];
  const int tid = threadIdx.x;
  const int wid = tid >> 6, lane = tid & 63;
  const int g = lane >> 4, c = lane & 15;
  const int job = blockIdx.x * 4 + wid;       // 6144 jobs x 256 positions
  const int b = job / 384;
  const size_t pos0 = (size_t)job * 256;
  const int fl = flag[0];

  // input-layer B-frags: rows 0-5 = W_lin (for md_hi), rows 8-13 = W_lin
  // (for md_lo), row 6 = rep_bias (bias rides on A[k=6]=1.0)
  bf16x8 BinH[2], BinL[2];
#pragma unroll
  for (int ct = 0; ct < 2; ++ct)
#pragma unroll
    for (int e = 0; e < 8; ++e) {
      float w = 0.f;
      if (e < 6) { if (g < 2) w = W_lin[e * 32 + ct * 16 + c]; }
      else if (e == 6 && g == 0) w = rep_bias[b * 32 + ct * 16 + c];
      short hh, ll; split2(w, hh, ll);
      BinH[ct][e] = hh; BinL[ct][e] = ll;
    }

  bf16x8 Bh[3][2], Bl[3][2];
#pragma unroll
  for (int d = 0; d < 3; ++d)
#pragma unroll
    for (int ct = 0; ct < 2; ++ct)
#pragma unroll
      for (int e = 0; e < 8; ++e) {
        const float w = Wd[d * 1024 + (g * 8 + e) * 32 + ct * 16 + c];
        short hh, ll; split2(w, hh, ll);
        Bh[d][ct][e] = hh; Bl[d][ct][e] = ll;
      }
  float bias_v[3][2];
#pragma unroll
  for (int d = 0; d < 3; ++d) {
    bias_v[d][0] = bd[d * 32 + c];
    bias_v[d][1] = bd[d * 32 + 16 + c];
  }
  const float w0 = W_out[c], w1 = W_out[16 + c];
  const float bo = b_out[0];
  float* bufA = ldsA[wid];
  float* bufB = ldsB[wid];

  // prefetch tile 0: metadata (pos = tb + c) and mask
  float mv[6];
  uint32_t mk;
  {
    const float* mrow = md + (pos0 + c) * 6;
    const float2 a01 = *(const float2*)(mrow);
    const float2 a23 = *(const float2*)(mrow + 2);
    const float2 a45 = *(const float2*)(mrow + 4);
    mv[0] = a01.x; mv[1] = a01.y; mv[2] = a23.x;
    mv[3] = a23.y; mv[4] = a45.x; mv[5] = a45.y;
    mk = fl ? (uint32_t)((const uint8_t*)maskp)[pos0 + c]
            : ((const uint32_t*)maskp)[pos0 + c];
  }

  for (int t = 0; t < 16; ++t) {
    const size_t tb = pos0 + (size_t)t * 16;

    // issue next tile's loads first (hidden under this tile's compute)
    float mvn[6];
    uint32_t mkn = 0;
    if (t < 15) {
      const float* mrow = md + (tb + 16 + c) * 6;
      const float2 a01 = *(const float2*)(mrow);
      const float2 a23 = *(const float2*)(mrow + 2);
      const float2 a45 = *(const float2*)(mrow + 4);
      mvn[0] = a01.x; mvn[1] = a01.y; mvn[2] = a23.x;
      mvn[3] = a23.y; mvn[4] = a45.x; mvn[5] = a45.y;
      mkn = fl ? (uint32_t)((const uint8_t*)maskp)[tb + 16 + c]
               : ((const uint32_t*)maskp)[tb + 16 + c];
    }

    // build A_in: k0-5 = md_hi, k6 = 1.0, k8-13 = md_lo
    bf16x8 Ain;
#pragma unroll
    for (int i = 0; i < 6; ++i) {
      short hh, ll; split2(mv[i], hh, ll);
      Ain[i] = (g == 0) ? hh : ((g == 1) ? ll : (short)0);
    }
    Ain[6] = (g == 0) ? (short)0x3F80 : (short)0;
    Ain[7] = 0;

    // input layer: 4 MFMAs, bias included
    f32x4 a0 = {0.f, 0.f, 0.f, 0.f}, a1 = {0.f, 0.f, 0.f, 0.f};
    a0 = __builtin_amdgcn_mfma_f32_16x16x32_bf16(Ain, BinH[0], a0, 0, 0, 0);
    a0 = __builtin_amdgcn_mfma_f32_16x16x32_bf16(Ain, BinL[0], a0, 0, 0, 0);
    a1 = __builtin_amdgcn_mfma_f32_16x16x32_bf16(Ain, BinH[1], a1, 0, 0, 0);
    a1 = __builtin_amdgcn_mfma_f32_16x16x32_bf16(Ain, BinL[1], a1, 0, 0, 0);
    // no relu on input layer

    // transpose input-layer output (C-layout -> A-frag) via bufA
    bf16x8 ah, al;
#pragma unroll
    for (int r = 0; r < 4; ++r) {
      bufA[(g * 4 + r) * 36 + c] = a0[r];
      bufA[(g * 4 + r) * 36 + 16 + c] = a1[r];
    }
#pragma unroll
    for (int e = 0; e < 8; ++e) {
      const float h = bufA[c * 36 + g * 8 + e];
      short hh, ll; split2(h, hh, ll);
      ah[e] = hh; al[e] = ll;
    }

#pragma unroll
    for (int d = 0; d < 3; ++d) {
      f32x4 d0 = {0.f, 0.f, 0.f, 0.f}, d1 = {0.f, 0.f, 0.f, 0.f};
      d0 = __builtin_amdgcn_mfma_f32_16x16x32_bf16(ah, Bh[d][0], d0, 0, 0, 0);
      d0 = __builtin_amdgcn_mfma_f32_16x16x32_bf16(al, Bh[d][0], d0, 0, 0, 0);
      d0 = __builtin_amdgcn_mfma_f32_16x16x32_bf16(ah, Bl[d][0], d0, 0, 0, 0);
      d1 = __builtin_amdgcn_mfma_f32_16x16x32_bf16(ah, Bh[d][1], d1, 0, 0, 0);
      d1 = __builtin_amdgcn_mfma_f32_16x16x32_bf16(al, Bh[d][1], d1, 0, 0, 0);
      d1 = __builtin_amdgcn_mfma_f32_16x16x32_bf16(ah, Bl[d][1], d1, 0, 0, 0);
#pragma unroll
      for (int r = 0; r < 4; ++r) {
        d0[r] = fmaxf(d0[r] + bias_v[d][0], 0.f);
        d1[r] = fmaxf(d1[r] + bias_v[d][1], 0.f);
      }
      if (d < 2) {
        float* buf = (d == 0) ? bufB : bufA;
#pragma unroll
        for (int r = 0; r < 4; ++r) {
          buf[(g * 4 + r) * 36 + c] = d0[r];
          buf[(g * 4 + r) * 36 + 16 + c] = d1[r];
        }
#pragma unroll
        for (int e = 0; e < 8; ++e) {
          const float h = buf[c * 36 + g * 8 + e];
          short hh, ll; split2(h, hh, ll);
          ah[e] = hh; al[e] = ll;
        }
      } else {
        // epilogue: s_r = d0*W_out[c] + d1*W_out[16+c]; reduce over 16 cols
#pragma unroll
        for (int r = 0; r < 4; ++r) {
          const float sr = fmaf(d0[r], w0, d1[r] * w1);
          bufB[(g * 4 + r) * 36 + c] = sr;
        }
        float u = 0.f;
#pragma unroll
        for (int i = 0; i < 4; ++i) u += bufB[c * 36 + g + 4 * i];
        u += __shfl_xor(u, 16);
        u += __shfl_xor(u, 32);
        if (g == 0) out[tb + c] = mk ? (u + bo) : 0.0f;
      }
    }

#pragma unroll
    for (int i = 0; i < 6; ++i) mv[i] = mvn[i];
    mk = mkn;
  }
}

extern "C" void kernel_launch(void* const* d_in, const int* in_sizes, int n_in,
                              void* d_out, int out_size, void* d_ws, size_t ws_size,
                              hipStream_t stream) {
  const float* Imodel   = (const float*)d_in[0];
  const float* Iobs     = (const float*)d_in[1];
  const float* metadata = (const float*)d_in[2];
  const void*  mask     = d_in[3];
  const int*   sample_size = (const int*)d_in[4];
  const float* W_img_in = (const float*)d_in[5];
  const float* b_img_in = (const float*)d_in[6];
  const float* W_img    = (const float*)d_in[7];
  const float* b_img    = (const float*)d_in[8];
  const float* W_lin_in = (const float*)d_in[9];
  const float* b_lin_in = (const float*)d_in[10];
  const float* W_mlp    = (const float*)d_in[11];
  const float* b_mlp    = (const float*)d_in[12];
  const float* W_out    = (const float*)d_in[13];
  const float* b_out    = (const float*)d_in[14];
  float* out = (float*)d_out;

  char* ws = (char*)d_ws;
  int*   flag     = (int*)(ws + WS_FLAG);
  int*   sel      = (int*)(ws + WS_SEL);
  int*   vint     = (int*)(ws + WS_VINT);
  int*   vbyte    = (int*)(ws + WS_VBYTE);
  float* partial  = (float*)(ws + WS_PART);
  float* rep_bias = (float*)(ws + WS_REPB);

  k_valid<<<NROW / 4, 256, 0, stream>>>(mask, vint, vbyte);
  k_select<<<BB, 64, 0, stream>>>(mask, vint, vbyte, sample_size, flag, sel);
  k_image<<<512, 256, 0, stream>>>(Imodel, Iobs, metadata, mask, flag, sel,
                                   sample_size, W_img_in, b_img_in, W_img,
                                   b_img, partial);
  k_rep<<<BB, 32, 0, stream>>>(partial, b_lin_in, rep_bias);
  k_scale<<<1536, 256, 0, stream>>>(metadata, mask, flag, W_lin_in, rep_bias,
                                    W_mlp, b_mlp, W_out, b_out, out);
}